// Round 8
// baseline (91.533 us; speedup 1.0000x reference)
//
#include <hip/hip_runtime.h>
#include <hip/hip_bf16.h>
#include <math.h>

// B=2048, N=16384, D=16
#define BB 2048
#define NN 16384
#define KAUG 32                 // augmented K (18 used, padded to MFMA K=32)
#define RSA 40                  // A LDS row stride in ushorts (80 B)
#define RSX 32                  // X LDS row stride in ushorts (64 B)
#define NSLICES 128             // 128 slices x 128 n
#define CHUNKS 8                // 8 x 16-n chunks per slice
#define MARGIN 40.0f            // drop tiles < 2^-40 of max: error ~1e-8 nats
#define LN2 0.6931471805599453f
#define LOG2E 1.4426950408889634f
#define LN2PI 1.8378770664093453f

typedef __attribute__((ext_vector_type(8))) short bf16x8;
typedef __attribute__((ext_vector_type(4))) float f32x4;

__device__ __forceinline__ float EXP2(float v) { return __builtin_amdgcn_exp2f(v); }

__device__ __forceinline__ unsigned pack_bf2(float a, float b) {
    __hip_bfloat162 h = __float22bfloat162_rn(make_float2(a, b));
    union { __hip_bfloat162 h2; unsigned u; } cvt;
    cvt.h2 = h;
    return cvt.u;
}
__device__ __forceinline__ float lo16f(unsigned u) { return __uint_as_float(u << 16); }
__device__ __forceinline__ float hi16f(unsigned u) { return __uint_as_float(u & 0xFFFF0000u); }

// monotone float <-> uint key (for atomicMax on floats; exact, order-free)
__device__ __forceinline__ unsigned fkey(float f) {
    unsigned u = __float_as_uint(f);
    return u ^ (unsigned)(((int)u >> 31) | 0x80000000);
}
__device__ __forceinline__ float funkey(unsigned k) {
    unsigned u = (k & 0x80000000u) ? (k & 0x7FFFFFFFu) : ~k;
    return __uint_as_float(u);
}

// ---------------------------------------------------------------------------
// K1: MFMA max-pass. Grid = 128 slices x 16 bgrps. Per block: prep augmented
// split-bf16 A/X rows into LDS (echo panels to global for K2), then per
// 16x16 tile compute acc (= base-2 exponent) and store g-merged chunk maxes.
// Slice max -> plain store; global per-b max via keyed atomicMax (exact).
// NO exp2, NO sums here.
// ---------------------------------------------------------------------------
__global__ __launch_bounds__(256, 4) void kde_max(
    const float* __restrict__ x, const float* __restrict__ mu,
    const float* __restrict__ sigt, const float* __restrict__ wt,
    ushort* __restrict__ Aph, ushort* __restrict__ Apl,
    ushort* __restrict__ Xph, ushort* __restrict__ Xpl,
    float* __restrict__ slicemax, float* __restrict__ chunkmax,
    unsigned* __restrict__ gkey)
{
    __shared__ ushort AhL[128 * RSA], AlL[128 * RSA];
    __shared__ ushort XhL[128 * RSX], XlL[128 * RSX];

    const int tid   = threadIdx.x;
    const int slice = blockIdx.x >> 4;
    const int bgrp  = blockIdx.x & 15;

    // ---------------- prep one augmented row per thread -------------------
    {
        float v[KAUG];
        #pragma unroll
        for (int k = 18; k < KAUG; ++k) v[k] = 0.f;
        ushort *dh, *dl, *eh = nullptr, *el = nullptr;
        if (tid < 128) {
            int n = slice * 128 + tid;
            const float4* m4 = (const float4*)(mu + (size_t)n * 16);
            float4 a = m4[0], b = m4[1], c = m4[2], d = m4[3];
            float r[16];
            *(float4*)(r + 0) = a; *(float4*)(r + 4) = b;
            *(float4*)(r + 8) = c; *(float4*)(r + 12) = d;
            float musq = 0.f;
            #pragma unroll
            for (int k = 0; k < 16; ++k) musq = fmaf(r[k], r[k], musq);
            float stv = sigt[n], wv2 = wt[n];
            float A2 = -0.5f * LOG2E * EXP2(-2.0f * LOG2E * stv);
            float C2 = -LOG2E * (16.f * stv + 8.f * LN2PI) + __log2f(wv2);
            #pragma unroll
            for (int k = 0; k < 16; ++k) v[k] = A2 * (-2.f * r[k]);
            v[16] = fmaf(A2, musq, C2);
            v[17] = A2;
            dh = AhL + tid * RSA;
            dl = AlL + tid * RSA;
            if (bgrp == 0) { eh = Aph + (size_t)n * KAUG; el = Apl + (size_t)n * KAUG; }
        } else {
            int b = bgrp * 128 + (tid - 128);
            const float4* x4 = (const float4*)(x + (size_t)b * 16);
            float4 a = x4[0], bb = x4[1], c = x4[2], d = x4[3];
            float r[16];
            *(float4*)(r + 0) = a;  *(float4*)(r + 4) = bb;
            *(float4*)(r + 8) = c;  *(float4*)(r + 12) = d;
            float xsq = 0.f;
            #pragma unroll
            for (int k = 0; k < 16; ++k) { v[k] = r[k]; xsq = fmaf(r[k], r[k], xsq); }
            v[16] = 1.0f;
            v[17] = xsq;
            dh = XhL + (tid - 128) * RSX;
            dl = XlL + (tid - 128) * RSX;
            if (slice == 0) { eh = Xph + (size_t)b * KAUG; el = Xpl + (size_t)b * KAUG; }
        }
        unsigned uh[16], ul[16];
        #pragma unroll
        for (int k = 0; k < 16; ++k) {
            unsigned h = pack_bf2(v[2*k], v[2*k+1]);
            unsigned l = pack_bf2(v[2*k]   - lo16f(h),
                                  v[2*k+1] - hi16f(h));
            uh[k] = h;  ul[k] = l;
        }
        uint4* ph = (uint4*)dh;
        uint4* pl = (uint4*)dl;
        #pragma unroll
        for (int k = 0; k < 4; ++k) {
            uint4 H = make_uint4(uh[4*k], uh[4*k+1], uh[4*k+2], uh[4*k+3]);
            uint4 L = make_uint4(ul[4*k], ul[4*k+1], ul[4*k+2], ul[4*k+3]);
            ph[k] = H;  pl[k] = L;
            if (eh) { ((uint4*)eh)[k] = H; ((uint4*)el)[k] = L; }
        }
    }
    __syncthreads();

    // ---------------- max pass --------------------------------------------
    const int lane = tid & 63;
    const int wv   = tid >> 6;
    const int l15  = lane & 15, g = lane >> 4;
    const int b0   = bgrp * 128 + wv * 32 + l15;

    bf16x8 bh[2], bl[2];
    #pragma unroll
    for (int bt = 0; bt < 2; ++bt) {
        int xr = wv * 32 + bt * 16 + l15;
        bh[bt] = *(const bf16x8*)(XhL + xr * RSX + g * 8);
        bl[bt] = *(const bf16x8*)(XlL + xr * RSX + g * 8);
    }

    float M0 = -INFINITY, M1 = -INFINITY;
    #pragma unroll 2
    for (int c = 0; c < CHUNKS; ++c) {
        int ar = c * 16 + l15;
        bf16x8 ah = *(const bf16x8*)(AhL + ar * RSA + g * 8);
        bf16x8 al = *(const bf16x8*)(AlL + ar * RSA + g * 8);
        f32x4 a0 = {0.f, 0.f, 0.f, 0.f};
        a0 = __builtin_amdgcn_mfma_f32_16x16x32_bf16(al, bh[0], a0, 0, 0, 0);
        a0 = __builtin_amdgcn_mfma_f32_16x16x32_bf16(ah, bl[0], a0, 0, 0, 0);
        a0 = __builtin_amdgcn_mfma_f32_16x16x32_bf16(ah, bh[0], a0, 0, 0, 0);
        float cm0 = fmaxf(fmaxf(a0[0], a0[1]), fmaxf(a0[2], a0[3]));
        cm0 = fmaxf(cm0, __shfl_xor(cm0, 16, 64));
        cm0 = fmaxf(cm0, __shfl_xor(cm0, 32, 64));
        f32x4 a1 = {0.f, 0.f, 0.f, 0.f};
        a1 = __builtin_amdgcn_mfma_f32_16x16x32_bf16(al, bh[1], a1, 0, 0, 0);
        a1 = __builtin_amdgcn_mfma_f32_16x16x32_bf16(ah, bl[1], a1, 0, 0, 0);
        a1 = __builtin_amdgcn_mfma_f32_16x16x32_bf16(ah, bh[1], a1, 0, 0, 0);
        float cm1 = fmaxf(fmaxf(a1[0], a1[1]), fmaxf(a1[2], a1[3]));
        cm1 = fmaxf(cm1, __shfl_xor(cm1, 16, 64));
        cm1 = fmaxf(cm1, __shfl_xor(cm1, 32, 64));
        if (lane < 16) {
            chunkmax[(size_t)(slice * 8 + c) * BB + b0]      = cm0;
            chunkmax[(size_t)(slice * 8 + c) * BB + b0 + 16] = cm1;
        }
        M0 = fmaxf(M0, cm0);
        M1 = fmaxf(M1, cm1);
    }

    if (lane < 16) {
        slicemax[(size_t)slice * BB + b0]      = M0;
        slicemax[(size_t)slice * BB + b0 + 16] = M1;
        unsigned k0 = fkey(M0);
        if (k0 > gkey[b0])      atomicMax(&gkey[b0], k0);
        unsigned k1 = fkey(M1);
        if (k1 > gkey[b0 + 16]) atomicMax(&gkey[b0 + 16], k1);
    }
}

// ---------------------------------------------------------------------------
// K2: sparse gather-sum. 128 blocks, one 16-b tile each; wave w scans slices
// w::4, gated by slicemax then chunkmax vs global max M (margin 40 -> exact
// within 2^-40). Surviving tiles: 3-MFMA recompute (bitwise = K1) + exp2 sum.
// Fixed order everywhere -> deterministic. Writes out directly.
// ---------------------------------------------------------------------------
__global__ __launch_bounds__(256) void kde_gather(
    const ushort* __restrict__ Aph, const ushort* __restrict__ Apl,
    const ushort* __restrict__ Xph, const ushort* __restrict__ Xpl,
    const float* __restrict__ slicemax, const float* __restrict__ chunkmax,
    const unsigned* __restrict__ gkey, float* __restrict__ out)
{
    __shared__ float sS[4][16];
    const int tid  = threadIdx.x;
    const int lane = tid & 63;
    const int wv   = tid >> 6;
    const int l15  = lane & 15, g = lane >> 4;
    const int b    = blockIdx.x * 16 + l15;

    const float M = funkey(gkey[b]);
    bf16x8 bh = *(const bf16x8*)(Xph + (size_t)b * KAUG + g * 8);
    bf16x8 bl = *(const bf16x8*)(Xpl + (size_t)b * KAUG + g * 8);

    float S = 0.f;
    for (int sl = wv; sl < NSLICES; sl += 4) {
        float sm = slicemax[(size_t)sl * BB + b];
        if (!__any(sm >= M - MARGIN)) continue;
        #pragma unroll
        for (int c = 0; c < CHUNKS; ++c) {
            float cm = chunkmax[(size_t)(sl * 8 + c) * BB + b];
            if (!__any(cm >= M - MARGIN)) continue;
            int n = sl * 128 + c * 16 + l15;
            bf16x8 ah = *(const bf16x8*)(Aph + (size_t)n * KAUG + g * 8);
            bf16x8 al = *(const bf16x8*)(Apl + (size_t)n * KAUG + g * 8);
            f32x4 acc = {0.f, 0.f, 0.f, 0.f};
            acc = __builtin_amdgcn_mfma_f32_16x16x32_bf16(al, bh, acc, 0, 0, 0);
            acc = __builtin_amdgcn_mfma_f32_16x16x32_bf16(ah, bl, acc, 0, 0, 0);
            acc = __builtin_amdgcn_mfma_f32_16x16x32_bf16(ah, bh, acc, 0, 0, 0);
            S += (EXP2(acc[0] - M) + EXP2(acc[1] - M))
               + (EXP2(acc[2] - M) + EXP2(acc[3] - M));
        }
    }
    // merge the 4 lane-groups (rows), then the 4 waves (slice stripes)
    S += __shfl_xor(S, 16, 64);
    S += __shfl_xor(S, 32, 64);
    if (lane < 16) sS[wv][l15] = S;
    __syncthreads();
    if (tid < 16) {
        float St = (sS[0][tid] + sS[1][tid]) + (sS[2][tid] + sS[3][tid]);
        int bb = blockIdx.x * 16 + tid;
        out[bb] = (funkey(gkey[bb]) + __log2f(St)) * LN2;
    }
}

extern "C" void kernel_launch(void* const* d_in, const int* in_sizes, int n_in,
                              void* d_out, int out_size, void* d_ws, size_t ws_size,
                              hipStream_t stream) {
    const float* x  = (const float*)d_in[0];
    const float* mu = (const float*)d_in[1];
    const float* st = (const float*)d_in[2];
    const float* w  = (const float*)d_in[3];
    float* out = (float*)d_out;

    char* ws = (char*)d_ws;
    unsigned* gkey   = (unsigned*)ws;                               //   8 KB
    float* slicemax  = (float*)(ws + 8192);                         //   1 MB
    float* chunkmax  = (float*)(ws + 8192 + (1u << 20));            //   8 MB
    ushort* Aph      = (ushort*)(ws + 8192 + (9u << 20));           //   1 MB
    ushort* Apl      = (ushort*)(ws + 8192 + (10u << 20));          //   1 MB
    ushort* Xph      = (ushort*)(ws + 8192 + (11u << 20));          // 128 KB
    ushort* Xpl      = (ushort*)(ws + 8192 + (11u << 20) + (128u << 10));

    hipMemsetAsync(gkey, 0, BB * sizeof(unsigned), stream);  // key(0) < every real key

    hipLaunchKernelGGL(kde_max, dim3(NSLICES * 16), dim3(256), 0, stream,
                       x, mu, st, w, Aph, Apl, Xph, Xpl, slicemax, chunkmax, gkey);
    hipLaunchKernelGGL(kde_gather, dim3(BB / 16), dim3(256), 0, stream,
                       Aph, Apl, Xph, Xpl, slicemax, chunkmax, gkey, out);
}

// Round 9
// 23.283 us; speedup vs baseline: 3.9313x; 3.9313x over previous
//
#include <hip/hip_runtime.h>
#include <hip/hip_bf16.h>
#include <math.h>

// B=2048, N=16384, D=16
#define BB 2048
#define NN 16384
#define KAUG 32                 // augmented K (18 used, padded to MFMA K=32)
#define RSA 40                  // A LDS row stride in ushorts (80 B)
#define RSX 32                  // X LDS row stride in ushorts (64 B)
#define NSLICES 128
#define CHUNKS 8                // per slice; 1024 chunks of 16 n total
#define NCHUNK 1024
#define MARGIN 60.0f            // gate: keep chunks with meas-max >= M-60
#define LN2 0.6931471805599453f
#define LOG2E 1.4426950408889634f
#define LN2PI 1.8378770664093453f

typedef __attribute__((ext_vector_type(8))) short bf16x8;
typedef __attribute__((ext_vector_type(4))) float f32x4;

__device__ __forceinline__ float EXP2(float v) { return __builtin_amdgcn_exp2f(v); }

__device__ __forceinline__ unsigned pack_bf2(float a, float b) {
    __hip_bfloat162 h = __float22bfloat162_rn(make_float2(a, b));
    union { __hip_bfloat162 h2; unsigned u; } cvt;
    cvt.h2 = h;
    return cvt.u;
}
__device__ __forceinline__ float lo16f(unsigned u) { return __uint_as_float(u << 16); }
__device__ __forceinline__ float hi16f(unsigned u) { return __uint_as_float(u & 0xFFFF0000u); }

// ---------------------------------------------------------------------------
// K1: approximate max-pass. Grid = 128 slices x 16 bgrps, 256 thr.
// Prep: A rows split hi/lo bf16 (so measured e2 err ~ |e2|*2^-9 from X-side
// only, delta <~ 13 log2 units); X rows hi-only. 2 MFMAs per 16x16 tile give
// acc ~= base-2 exponent. Per-chunk maxes (g-merged) -> registers -> one
// transposed coalescable store chunkmax[b][1024]. No atomics. No exp2.
// ---------------------------------------------------------------------------
__global__ __launch_bounds__(256, 5) void kde_max(
    const float* __restrict__ x, const float* __restrict__ mu,
    const float* __restrict__ sigt, const float* __restrict__ wt,
    float* __restrict__ chunkmax)
{
    __shared__ ushort AhL[128 * RSA], AlL[128 * RSA];   // 10 KB + 10 KB
    __shared__ ushort XhL[128 * RSX];                   //  8 KB

    const int tid   = threadIdx.x;
    const int slice = blockIdx.x >> 4;
    const int bgrp  = blockIdx.x & 15;

    // ---------------- prep one augmented row per thread -------------------
    if (tid < 128) {
        int n = slice * 128 + tid;
        const float4* m4 = (const float4*)(mu + (size_t)n * 16);
        float4 a = m4[0], b = m4[1], c = m4[2], d = m4[3];
        float r[16];
        *(float4*)(r + 0) = a; *(float4*)(r + 4) = b;
        *(float4*)(r + 8) = c; *(float4*)(r + 12) = d;
        float musq = 0.f;
        #pragma unroll
        for (int k = 0; k < 16; ++k) musq = fmaf(r[k], r[k], musq);
        float stv = sigt[n], wv2 = wt[n];
        float A2 = -0.5f * LOG2E * EXP2(-2.0f * LOG2E * stv);
        float C2 = -LOG2E * (16.f * stv + 8.f * LN2PI) + __log2f(wv2);
        float v[KAUG];
        #pragma unroll
        for (int k = 0; k < 16; ++k) v[k] = A2 * (-2.f * r[k]);
        v[16] = fmaf(A2, musq, C2);
        v[17] = A2;
        #pragma unroll
        for (int k = 18; k < KAUG; ++k) v[k] = 0.f;
        unsigned uh[16], ul[16];
        #pragma unroll
        for (int k = 0; k < 16; ++k) {
            unsigned h = pack_bf2(v[2*k], v[2*k+1]);
            unsigned l = pack_bf2(v[2*k]   - lo16f(h),
                                  v[2*k+1] - hi16f(h));
            uh[k] = h;  ul[k] = l;
        }
        uint4* ph = (uint4*)(AhL + tid * RSA);
        uint4* pl = (uint4*)(AlL + tid * RSA);
        #pragma unroll
        for (int k = 0; k < 4; ++k) {
            ph[k] = make_uint4(uh[4*k], uh[4*k+1], uh[4*k+2], uh[4*k+3]);
            pl[k] = make_uint4(ul[4*k], ul[4*k+1], ul[4*k+2], ul[4*k+3]);
        }
    } else {
        int b = bgrp * 128 + (tid - 128);
        const float4* x4 = (const float4*)(x + (size_t)b * 16);
        float4 a = x4[0], bb = x4[1], c = x4[2], d = x4[3];
        float r[16];
        *(float4*)(r + 0) = a;  *(float4*)(r + 4) = bb;
        *(float4*)(r + 8) = c;  *(float4*)(r + 12) = d;
        float xsq = 0.f;
        #pragma unroll
        for (int k = 0; k < 16; ++k) xsq = fmaf(r[k], r[k], xsq);
        unsigned uh[16];
        #pragma unroll
        for (int k = 0; k < 8; ++k) uh[k] = pack_bf2(r[2*k], r[2*k+1]);
        uh[8] = pack_bf2(1.0f, xsq);
        #pragma unroll
        for (int k = 9; k < 16; ++k) uh[k] = 0u;
        uint4* ph = (uint4*)(XhL + (tid - 128) * RSX);
        #pragma unroll
        for (int k = 0; k < 4; ++k)
            ph[k] = make_uint4(uh[4*k], uh[4*k+1], uh[4*k+2], uh[4*k+3]);
    }
    __syncthreads();

    // ---------------- max pass (2 MFMAs per tile) --------------------------
    const int lane = tid & 63;
    const int wv   = tid >> 6;
    const int l15  = lane & 15, g = lane >> 4;

    bf16x8 bh0 = *(const bf16x8*)(XhL + (wv * 32 + l15) * RSX + g * 8);
    bf16x8 bh1 = *(const bf16x8*)(XhL + (wv * 32 + 16 + l15) * RSX + g * 8);

    float cmA[CHUNKS], cmB[CHUNKS];
    #pragma unroll
    for (int c = 0; c < CHUNKS; ++c) {
        int ar = c * 16 + l15;
        bf16x8 ah = *(const bf16x8*)(AhL + ar * RSA + g * 8);
        bf16x8 al = *(const bf16x8*)(AlL + ar * RSA + g * 8);
        f32x4 a0 = {0.f, 0.f, 0.f, 0.f};
        a0 = __builtin_amdgcn_mfma_f32_16x16x32_bf16(al, bh0, a0, 0, 0, 0);
        a0 = __builtin_amdgcn_mfma_f32_16x16x32_bf16(ah, bh0, a0, 0, 0, 0);
        float c0 = fmaxf(fmaxf(a0[0], a0[1]), fmaxf(a0[2], a0[3]));
        c0 = fmaxf(c0, __shfl_xor(c0, 16, 64));
        c0 = fmaxf(c0, __shfl_xor(c0, 32, 64));
        f32x4 a1 = {0.f, 0.f, 0.f, 0.f};
        a1 = __builtin_amdgcn_mfma_f32_16x16x32_bf16(al, bh1, a1, 0, 0, 0);
        a1 = __builtin_amdgcn_mfma_f32_16x16x32_bf16(ah, bh1, a1, 0, 0, 0);
        float c1 = fmaxf(fmaxf(a1[0], a1[1]), fmaxf(a1[2], a1[3]));
        c1 = fmaxf(c1, __shfl_xor(c1, 16, 64));
        c1 = fmaxf(c1, __shfl_xor(c1, 32, 64));
        cmA[c] = c0;
        cmB[c] = c1;
    }

    if (lane < 16) {
        int b0 = bgrp * 128 + wv * 32 + l15;
        float4* p0 = (float4*)(chunkmax + (size_t)b0 * NCHUNK + slice * 8);
        p0[0] = make_float4(cmA[0], cmA[1], cmA[2], cmA[3]);
        p0[1] = make_float4(cmA[4], cmA[5], cmA[6], cmA[7]);
        float4* p1 = (float4*)(chunkmax + (size_t)(b0 + 16) * NCHUNK + slice * 8);
        p1[0] = make_float4(cmB[0], cmB[1], cmB[2], cmB[3]);
        p1[1] = make_float4(cmB[4], cmB[5], cmB[6], cmB[7]);
    }
}

// ---------------------------------------------------------------------------
// K2: exact sparse gather. One wave per sample b (512 blocks x 256 thr).
// Lane-parallel gate: 16 coalesced loads cover all 1024 chunk maxes; wave
// max-reduce -> M; ballot -> survivor bitmasks; ~1-4 surviving chunks
// evaluated EXACTLY in fp32 from raw inputs (no bf16 in the value path; M
// cancels in M + log2(sum exp2(e2-M))). Fixed order -> deterministic.
// ---------------------------------------------------------------------------
__global__ __launch_bounds__(256) void kde_gather(
    const float* __restrict__ x, const float* __restrict__ mu,
    const float* __restrict__ sigt, const float* __restrict__ wt,
    const float* __restrict__ chunkmax, float* __restrict__ out)
{
    const int tid  = threadIdx.x;
    const int lane = tid & 63;
    const int b    = blockIdx.x * 4 + (tid >> 6);

    // x row (uniform within wave) + xsq, fp32 exact
    float xr[16];
    {
        const float4* x4 = (const float4*)(x + (size_t)b * 16);
        float4 a = x4[0], bb = x4[1], c = x4[2], d = x4[3];
        *(float4*)(xr + 0) = a;  *(float4*)(xr + 4) = bb;
        *(float4*)(xr + 8) = c;  *(float4*)(xr + 12) = d;
    }
    float xsq = 0.f;
    #pragma unroll
    for (int k = 0; k < 16; ++k) xsq = fmaf(xr[k], xr[k], xsq);

    // gate loads: all 1024 chunk maxes, coalesced
    float cv[16];
    #pragma unroll
    for (int k = 0; k < 16; ++k)
        cv[k] = chunkmax[(size_t)b * NCHUNK + k * 64 + lane];

    // wave max-reduce -> M
    float M = cv[0];
    #pragma unroll
    for (int k = 1; k < 16; ++k) M = fmaxf(M, cv[k]);
    #pragma unroll
    for (int off = 1; off < 64; off <<= 1)
        M = fmaxf(M, __shfl_xor(M, off, 64));

    const float gate = M - MARGIN;
    float S = 0.f;

    #pragma unroll
    for (int k = 0; k < 16; ++k) {
        unsigned long long mk = __ballot(cv[k] >= gate);
        while (mk) {
            int bit = __builtin_ctzll(mk);
            mk &= mk - 1;
            int n = (k * 64 + bit) * 16 + (lane & 15);   // lanes 16-63 duplicate
            const float4* m4 = (const float4*)(mu + (size_t)n * 16);
            float4 ma = m4[0], mb = m4[1], mc = m4[2], md = m4[3];
            float mr[16];
            *(float4*)(mr + 0) = ma; *(float4*)(mr + 4) = mb;
            *(float4*)(mr + 8) = mc; *(float4*)(mr + 12) = md;
            float dotv = 0.f, musq = 0.f;
            #pragma unroll
            for (int j = 0; j < 16; ++j) {
                dotv = fmaf(xr[j], mr[j], dotv);
                musq = fmaf(mr[j], mr[j], musq);
            }
            float stv = sigt[n], wv2 = wt[n];
            float A2 = -0.5f * LOG2E * EXP2(-2.0f * LOG2E * stv);
            float C2 = -LOG2E * (16.f * stv + 8.f * LN2PI) + __log2f(wv2);
            float e2 = fmaf(A2, xsq - 2.f * dotv + musq, C2);
            float ex = EXP2(e2 - M);
            // sum the 16 distinct lanes (groups hold identical copies)
            ex += __shfl_xor(ex, 1, 64);
            ex += __shfl_xor(ex, 2, 64);
            ex += __shfl_xor(ex, 4, 64);
            ex += __shfl_xor(ex, 8, 64);
            S += ex;
        }
    }

    if (lane == 0) out[b] = (M + __log2f(S)) * LN2;
}

extern "C" void kernel_launch(void* const* d_in, const int* in_sizes, int n_in,
                              void* d_out, int out_size, void* d_ws, size_t ws_size,
                              hipStream_t stream) {
    const float* x  = (const float*)d_in[0];
    const float* mu = (const float*)d_in[1];
    const float* st = (const float*)d_in[2];
    const float* w  = (const float*)d_in[3];
    float* out = (float*)d_out;

    float* chunkmax = (float*)d_ws;                 // 2048 * 1024 * 4 = 8 MB

    hipLaunchKernelGGL(kde_max, dim3(NSLICES * 16), dim3(256), 0, stream,
                       x, mu, st, w, chunkmax);
    hipLaunchKernelGGL(kde_gather, dim3(BB / 4), dim3(256), 0, stream,
                       x, mu, st, w, chunkmax, out);
}